// Round 1
// baseline (1320.066 us; speedup 1.0000x reference)
//
#include <hip/hip_runtime.h>

#define NN 40000
#define NE 640000

static __device__ __forceinline__ float lrelu(float x) { return x > 0.0f ? x : 0.2f * x; }

// Monotonic uint encoding of float for atomicMax-based segment max.
static __device__ __forceinline__ unsigned fkey(float f) {
    unsigned u = __float_as_uint(f);
    return (u & 0x80000000u) ? ~u : (u | 0x80000000u);
}
static __device__ __forceinline__ float funkey(unsigned u) {
    return (u & 0x80000000u) ? __uint_as_float(u & 0x7FFFFFFFu) : __uint_as_float(~u);
}

// ---------------- GEMM: Y[row][c] = sum_k X[row][k] * W[k][c] ----------------
// blockDim.x == Fout (64 or 128); one block per row; X row staged in LDS.
__global__ void k_gemm(const float* __restrict__ X, const float* __restrict__ W,
                       float* __restrict__ Y, int Fin, int Fout) {
    extern __shared__ float xs[];
    int row = blockIdx.x;
    for (int k = threadIdx.x; k < Fin; k += blockDim.x) xs[k] = X[(size_t)row * Fin + k];
    __syncthreads();
    int c = threadIdx.x;
    float acc = 0.0f;
#pragma unroll 8
    for (int k = 0; k < Fin; ++k) acc = fmaf(xs[k], W[k * Fout + c], acc);
    Y[(size_t)row * Fout + c] = acc;
}

// ---------------- degree / norm ----------------
__global__ void k_deg_init(float* __restrict__ deg) {
    int i = blockIdx.x * blockDim.x + threadIdx.x;
    if (i < NN) deg[i] = 1.0f;  // self loop
}
__global__ void k_deg_count(const int* __restrict__ dst, float* __restrict__ deg) {
    int e = blockIdx.x * blockDim.x + threadIdx.x;
    if (e < NE) atomicAdd(&deg[dst[e]], 1.0f);
}
__global__ void k_deg_inv(float* __restrict__ deg) {
    int i = blockIdx.x * blockDim.x + threadIdx.x;
    if (i < NN) deg[i] = rsqrtf(deg[i]);
}

// ---------------- GCN aggregation ----------------
__global__ void k_gcn_self(const float* __restrict__ h, const float* __restrict__ dinv,
                           float* __restrict__ acc, int logF) {
    int idx = blockIdx.x * blockDim.x + threadIdx.x;
    int i = idx >> logF;
    if (i < NN) {
        float di = dinv[i];
        acc[idx] = h[idx] * di * di;
    }
}
__global__ void k_gcn_edge(const int* __restrict__ src, const int* __restrict__ dst,
                           const float* __restrict__ h, const float* __restrict__ dinv,
                           float* __restrict__ acc, int logF) {
    long long idx = (long long)blockIdx.x * blockDim.x + threadIdx.x;
    int e = (int)(idx >> logF);
    int F = 1 << logF;
    int c = (int)(idx & (F - 1));
    if (e < NE) {
        int s = src[e], d = dst[e];
        atomicAdd(&acc[(size_t)d * F + c], h[(size_t)s * F + c] * dinv[s] * dinv[d]);
    }
}
__global__ void k_bias_relu(const float* __restrict__ acc, const float* __restrict__ b,
                            float* __restrict__ out, int logF) {
    int idx = blockIdx.x * blockDim.x + threadIdx.x;
    int i = idx >> logF;
    int c = idx & ((1 << logF) - 1);
    if (i < NN) out[idx] = fmaxf(acc[idx] + b[c], 0.0f);
}

// ---------------- GAT ----------------
// per-node attention scalars: asrc[i] = hg[i] . a_src ; adst[i] = hg[i] . a_dst
__global__ void k_gat_scalars(const float* __restrict__ hg, const float* __restrict__ a_s,
                              const float* __restrict__ a_d, float* __restrict__ asrc,
                              float* __restrict__ adst, int F) {
    int node = blockIdx.x * (blockDim.x >> 6) + (threadIdx.x >> 6);
    int lane = threadIdx.x & 63;
    if (node >= NN) return;
    float s = 0.0f, d = 0.0f;
    for (int c = lane; c < F; c += 64) {
        float v = hg[(size_t)node * F + c];
        s += v * a_s[c];
        d += v * a_d[c];
    }
    for (int off = 32; off; off >>= 1) {
        s += __shfl_down(s, off);
        d += __shfl_down(d, off);
    }
    if (lane == 0) {
        asrc[node] = s;
        adst[node] = d;
    }
}
// self-logit + max init
__global__ void k_gat_self_init(const float* __restrict__ asrc, const float* __restrict__ adst,
                                float* __restrict__ slog, unsigned* __restrict__ mxu) {
    int i = blockIdx.x * blockDim.x + threadIdx.x;
    if (i < NN) {
        float sl = lrelu(asrc[i] + adst[i]);
        slog[i] = sl;
        mxu[i] = fkey(sl);
    }
}
__global__ void k_gat_max_edge(const int* __restrict__ src, const int* __restrict__ dst,
                               const float* __restrict__ asrc, const float* __restrict__ adst,
                               unsigned* __restrict__ mxu) {
    int e = blockIdx.x * blockDim.x + threadIdx.x;
    if (e < NE) {
        int s = src[e], d = dst[e];
        atomicMax(&mxu[d], fkey(lrelu(asrc[s] + adst[d])));
    }
}
// decode max to float (in place), init z with self term
__global__ void k_gat_z_init(float* __restrict__ mx, const float* __restrict__ slog,
                             float* __restrict__ z) {
    int i = blockIdx.x * blockDim.x + threadIdx.x;
    if (i < NN) {
        float m = funkey(((const unsigned*)mx)[i]);
        mx[i] = m;
        z[i] = __expf(slog[i] - m) == __expf(slog[i] - m) ? expf(slog[i] - m) : 0.0f;
        z[i] = expf(slog[i] - m);
    }
}
__global__ void k_gat_sum_edge(const int* __restrict__ src, const int* __restrict__ dst,
                               const float* __restrict__ asrc, const float* __restrict__ adst,
                               const float* __restrict__ mx, float* __restrict__ ev,
                               float* __restrict__ z) {
    int e = blockIdx.x * blockDim.x + threadIdx.x;
    if (e < NE) {
        int s = src[e], d = dst[e];
        float w = expf(lrelu(asrc[s] + adst[d]) - mx[d]);
        ev[e] = w;
        atomicAdd(&z[d], w);
    }
}
// zinv, self alpha
__global__ void k_gat_fin(float* __restrict__ z, const float* __restrict__ mx,
                          float* __restrict__ slog) {
    int i = blockIdx.x * blockDim.x + threadIdx.x;
    if (i < NN) {
        float zi = 1.0f / z[i];
        z[i] = zi;
        slog[i] = expf(slog[i] - mx[i]) * zi;  // alpha for self loop
    }
}
__global__ void k_gat_out_init(const float* __restrict__ hg, const float* __restrict__ aself,
                               float* __restrict__ out, int logF) {
    int idx = blockIdx.x * blockDim.x + threadIdx.x;
    int i = idx >> logF;
    if (i < NN) out[idx] = hg[idx] * aself[i];
}
__global__ void k_gat_out_edge(const int* __restrict__ src, const int* __restrict__ dst,
                               const float* __restrict__ hg, const float* __restrict__ ev,
                               const float* __restrict__ zinv, float* __restrict__ out,
                               int logF) {
    long long idx = (long long)blockIdx.x * blockDim.x + threadIdx.x;
    int e = (int)(idx >> logF);
    int F = 1 << logF;
    int c = (int)(idx & (F - 1));
    if (e < NE) {
        int s = src[e], d = dst[e];
        atomicAdd(&out[(size_t)d * F + c], hg[(size_t)s * F + c] * ev[e] * zinv[d]);
    }
}
__global__ void k_bias_add(float* __restrict__ out, const float* __restrict__ b, int logF) {
    int idx = blockIdx.x * blockDim.x + threadIdx.x;
    int i = idx >> logF;
    int c = idx & ((1 << logF) - 1);
    if (i < NN) out[idx] += b[c];
}

// ---------------- host-side helpers ----------------
static void gcn_layer(const float* X, const float* W, const float* b, const float* dinv,
                      const int* src, const int* dst, float* h_tmp, float* acc_tmp,
                      float* out, int Fin, int Fout, hipStream_t stream) {
    const int TB = 256;
    int logF = (Fout == 128) ? 7 : 6;
    int gNF = (NN * Fout + TB - 1) / TB;
    long long ef = (long long)NE * Fout;
    int gEF = (int)((ef + TB - 1) / TB);
    k_gemm<<<NN, Fout, Fin * sizeof(float), stream>>>(X, W, h_tmp, Fin, Fout);
    k_gcn_self<<<gNF, TB, 0, stream>>>(h_tmp, dinv, acc_tmp, logF);
    k_gcn_edge<<<gEF, TB, 0, stream>>>(src, dst, h_tmp, dinv, acc_tmp, logF);
    k_bias_relu<<<gNF, TB, 0, stream>>>(acc_tmp, b, out, logF);
}

static void gat_layer(const float* X, const float* W, const float* a_s, const float* a_d,
                      const float* b, const int* src, const int* dst, float* hg, float* asrc,
                      float* adst, float* mx, float* z, float* slog, float* ev, float* out,
                      int F, hipStream_t stream) {
    const int TB = 256;
    int logF = (F == 128) ? 7 : 6;
    int gN = (NN + TB - 1) / TB;
    int gE = (NE + TB - 1) / TB;
    int gNF = (NN * F + TB - 1) / TB;
    long long efl = (long long)NE * F;
    int gEF = (int)((efl + TB - 1) / TB);
    int gScal = (NN + 3) / 4;  // 4 nodes per 256-thread block

    k_gemm<<<NN, F, F * sizeof(float), stream>>>(X, W, hg, F, F);
    k_gat_scalars<<<gScal, TB, 0, stream>>>(hg, a_s, a_d, asrc, adst, F);
    k_gat_self_init<<<gN, TB, 0, stream>>>(asrc, adst, slog, (unsigned*)mx);
    k_gat_max_edge<<<gE, TB, 0, stream>>>(src, dst, asrc, adst, (unsigned*)mx);
    k_gat_z_init<<<gN, TB, 0, stream>>>(mx, slog, z);
    k_gat_sum_edge<<<gE, TB, 0, stream>>>(src, dst, asrc, adst, mx, ev, z);
    k_gat_fin<<<gN, TB, 0, stream>>>(z, mx, slog);
    k_gat_out_init<<<gNF, TB, 0, stream>>>(hg, slog, out, logF);
    k_gat_out_edge<<<gEF, TB, 0, stream>>>(src, dst, hg, ev, z, out, logF);
    k_bias_add<<<gNF, TB, 0, stream>>>(out, b, logF);
}

extern "C" void kernel_launch(void* const* d_in, const int* in_sizes, int n_in,
                              void* d_out, int out_size, void* d_ws, size_t ws_size,
                              hipStream_t stream) {
    const float* x = (const float*)d_in[0];
    const int* src = (const int*)d_in[1];
    const int* dst = src + NE;
    const float* W1 = (const float*)d_in[2];
    const float* b1 = (const float*)d_in[3];
    const float* Wg1 = (const float*)d_in[4];
    const float* ag1s = (const float*)d_in[5];
    const float* ag1d = (const float*)d_in[6];
    const float* bg1 = (const float*)d_in[7];
    const float* W2 = (const float*)d_in[8];
    const float* b2 = (const float*)d_in[9];
    const float* Wg2 = (const float*)d_in[10];
    const float* ag2s = (const float*)d_in[11];
    const float* ag2d = (const float*)d_in[12];
    const float* bg2 = (const float*)d_in[13];

    float* enc = (float*)d_out;                  // [NN,128]
    float* dec = enc + (size_t)NN * 128;         // [NN,64]

    float* ws = (float*)d_ws;
    float* bufA = ws;                            // NN*128
    float* bufB = bufA + (size_t)NN * 128;       // NN*128
    float* dinv = bufB + (size_t)NN * 128;       // NN
    float* asrc = dinv + NN;                     // NN
    float* adst = asrc + NN;                     // NN
    float* mx = adst + NN;                       // NN
    float* zz = mx + NN;                         // NN
    float* slog = zz + NN;                       // NN
    float* ev = slog + NN;                       // NE

    const int TB = 256;
    int gN = (NN + TB - 1) / TB;
    int gE = (NE + TB - 1) / TB;

    // symmetric degree norm (shared by both GCN layers)
    k_deg_init<<<gN, TB, 0, stream>>>(dinv);
    k_deg_count<<<gE, TB, 0, stream>>>(dst, dinv);
    k_deg_inv<<<gN, TB, 0, stream>>>(dinv);

    // Layer 1: GCN 128->128 + ReLU  (result in bufB)
    gcn_layer(x, W1, b1, dinv, src, dst, bufA, enc /*scratch acc*/, bufB, 128, 128, stream);
    // Layer 2: GAT 128->128 -> encoded (d_out)
    gat_layer(bufB, Wg1, ag1s, ag1d, bg1, src, dst, bufA, asrc, adst, mx, zz, slog, ev, enc,
              128, stream);
    // Layer 3: GCN 128->64 + ReLU (result in bufB)
    gcn_layer(enc, W2, b2, dinv, src, dst, bufA, dec /*scratch acc*/, bufB, 128, 64, stream);
    // Layer 4: GAT 64->64 -> decoded (d_out tail)
    gat_layer(bufB, Wg2, ag2s, ag2d, bg2, src, dst, bufA, asrc, adst, mx, zz, slog, ev, dec,
              64, stream);
}

// Round 2
// 574.042 us; speedup vs baseline: 2.2996x; 2.2996x over previous
//
#include <hip/hip_runtime.h>

#define NN 40000
#define NE 640000
#define SCAN_T 1024
#define SCAN_PER 40  // 1024*40 = 40960 >= NN
#define CHUNK 256

static __device__ __forceinline__ float lrelu(float x) { return x > 0.0f ? x : 0.2f * x; }

// ---------------- GEMM: Y[row][c] = sum_k X[row][k] * W[k][c] ----------------
__global__ void k_gemm(const float* __restrict__ X, const float* __restrict__ W,
                       float* __restrict__ Y, int Fin, int Fout) {
    extern __shared__ float xs[];
    int row = blockIdx.x;
    for (int k = threadIdx.x; k < Fin; k += blockDim.x) xs[k] = X[(size_t)row * Fin + k];
    __syncthreads();
    int c = threadIdx.x;
    float acc = 0.0f;
#pragma unroll 8
    for (int k = 0; k < Fin; ++k) acc = fmaf(xs[k], W[k * Fout + c], acc);
    Y[(size_t)row * Fout + c] = acc;
}

// ---------------- CSR build ----------------
__global__ void k_zero_int(int* __restrict__ p, int n) {
    int i = blockIdx.x * blockDim.x + threadIdx.x;
    if (i < n) p[i] = 0;
}
__global__ void k_count(const int* __restrict__ dst, int* __restrict__ cnt) {
    int e = blockIdx.x * blockDim.x + threadIdx.x;
    if (e < NE) atomicAdd(&cnt[dst[e]], 1);
}
// single-block exclusive scan: rowptr[NN+1], cursor copy
__global__ void k_scan(const int* __restrict__ cnt, int* __restrict__ rowptr,
                       int* __restrict__ cursor) {
    __shared__ int tsum[SCAN_T];
    int t = threadIdx.x;
    int lo = t * SCAN_PER;
    int hi = lo + SCAN_PER;
    if (hi > NN) hi = NN;
    int s = 0;
    for (int i = lo; i < hi; ++i) s += cnt[i];
    tsum[t] = s;
    __syncthreads();
    for (int off = 1; off < SCAN_T; off <<= 1) {
        int v = (t >= off) ? tsum[t - off] : 0;
        __syncthreads();
        tsum[t] += v;
        __syncthreads();
    }
    int run = (t > 0) ? tsum[t - 1] : 0;
    for (int i = lo; i < hi; ++i) {
        rowptr[i] = run;
        cursor[i] = run;
        run += cnt[i];
    }
    if (t == SCAN_T - 1) rowptr[NN] = tsum[SCAN_T - 1];
}
__global__ void k_fill(const int* __restrict__ src, const int* __restrict__ dst,
                       int* __restrict__ cursor, int* __restrict__ csr_src) {
    int e = blockIdx.x * blockDim.x + threadIdx.x;
    if (e < NE) {
        int p = atomicAdd(&cursor[dst[e]], 1);
        csr_src[p] = src[e];
    }
}
__global__ void k_dinv(const int* __restrict__ rowptr, float* __restrict__ dinv) {
    int i = blockIdx.x * blockDim.x + threadIdx.x;
    if (i < NN) dinv[i] = rsqrtf(1.0f + (float)(rowptr[i + 1] - rowptr[i]));
}

// ---------------- GCN: gather aggregation, one block per dst node ----------------
// blockDim.x == F. out[d][c] = relu( dinv[d]*( h[d][c]*dinv[d] + sum_e dinv[s]*h[s][c] ) + b[c] )
__global__ void k_gcn_gather(const int* __restrict__ rowptr, const int* __restrict__ csr_src,
                             const float* __restrict__ h, const float* __restrict__ dinv,
                             const float* __restrict__ b, float* __restrict__ out, int F) {
    __shared__ int sbuf[CHUNK];
    __shared__ float wbuf[CHUNK];
    int d = blockIdx.x;
    int c = threadIdx.x;
    int beg = rowptr[d], end = rowptr[d + 1];
    float dd = dinv[d];
    float acc = h[(size_t)d * F + c] * dd;
    for (int base = beg; base < end; base += CHUNK) {
        int cnt = end - base;
        if (cnt > CHUNK) cnt = CHUNK;
        for (int j = c; j < cnt; j += F) {
            int s = csr_src[base + j];
            sbuf[j] = s;
            wbuf[j] = dinv[s];
        }
        __syncthreads();
        for (int j = 0; j < cnt; ++j) acc = fmaf(wbuf[j], h[(size_t)sbuf[j] * F + c], acc);
        __syncthreads();
    }
    out[(size_t)d * F + c] = fmaxf(fmaf(acc, dd, b[c]), 0.0f);
}

// ---------------- GAT per-node attention scalars ----------------
__global__ void k_gat_scalars(const float* __restrict__ hg, const float* __restrict__ a_s,
                              const float* __restrict__ a_d, float* __restrict__ asrc,
                              float* __restrict__ adst, int F) {
    int node = blockIdx.x * (blockDim.x >> 6) + (threadIdx.x >> 6);
    int lane = threadIdx.x & 63;
    if (node >= NN) return;
    float s = 0.0f, d = 0.0f;
    for (int c = lane; c < F; c += 64) {
        float v = hg[(size_t)node * F + c];
        s += v * a_s[c];
        d += v * a_d[c];
    }
    for (int off = 32; off; off >>= 1) {
        s += __shfl_down(s, off);
        d += __shfl_down(d, off);
    }
    if (lane == 0) {
        asrc[node] = s;
        adst[node] = d;
    }
}

// ---------------- GAT: fused softmax + gather, one block per dst node ----------------
// blockDim.x == F (64 or 128).
__global__ void k_gat_gather(const int* __restrict__ rowptr, const int* __restrict__ csr_src,
                             const float* __restrict__ hg, const float* __restrict__ asrc,
                             const float* __restrict__ adst, const float* __restrict__ b,
                             float* __restrict__ out, int F) {
    __shared__ int sbuf[CHUNK];
    __shared__ float wbuf[CHUNK];
    __shared__ float red[2];
    int d = blockIdx.x;
    int tid = threadIdx.x;
    int lane = tid & 63, wid = tid >> 6, nw = F >> 6;
    int beg = rowptr[d], end = rowptr[d + 1];
    float ad = adst[d];
    float slog = lrelu(asrc[d] + ad);

    // phase 1: segment max (incl. self)
    float lm = slog;
    for (int j = beg + tid; j < end; j += F) {
        int s = csr_src[j];
        lm = fmaxf(lm, lrelu(asrc[s] + ad));
    }
    for (int off = 32; off; off >>= 1) lm = fmaxf(lm, __shfl_xor(lm, off));
    if (lane == 0) red[wid] = lm;
    __syncthreads();
    float m = red[0];
    for (int w = 1; w < nw; ++w) m = fmaxf(m, red[w]);
    __syncthreads();

    // phase 2: denominator
    float lz = 0.0f;
    for (int j = beg + tid; j < end; j += F) {
        int s = csr_src[j];
        lz += __expf(lrelu(asrc[s] + ad) - m);
    }
    for (int off = 32; off; off >>= 1) lz += __shfl_xor(lz, off);
    if (lane == 0) red[wid] = lz;
    __syncthreads();
    float eself = __expf(slog - m);
    float z = eself;
    for (int w = 0; w < nw; ++w) z += red[w];
    float zi = 1.0f / z;
    __syncthreads();

    // phase 3: weighted gather
    int c = tid;
    float acc = hg[(size_t)d * F + c] * (eself * zi);
    for (int base = beg; base < end; base += CHUNK) {
        int cnt = end - base;
        if (cnt > CHUNK) cnt = CHUNK;
        for (int j = tid; j < cnt; j += F) {
            int s = csr_src[base + j];
            sbuf[j] = s;
            wbuf[j] = __expf(lrelu(asrc[s] + ad) - m) * zi;
        }
        __syncthreads();
        for (int j = 0; j < cnt; ++j) acc = fmaf(wbuf[j], hg[(size_t)sbuf[j] * F + c], acc);
        __syncthreads();
    }
    out[(size_t)d * F + c] = acc + b[c];
}

extern "C" void kernel_launch(void* const* d_in, const int* in_sizes, int n_in,
                              void* d_out, int out_size, void* d_ws, size_t ws_size,
                              hipStream_t stream) {
    const float* x = (const float*)d_in[0];
    const int* src = (const int*)d_in[1];
    const int* dst = src + NE;
    const float* W1 = (const float*)d_in[2];
    const float* b1 = (const float*)d_in[3];
    const float* Wg1 = (const float*)d_in[4];
    const float* ag1s = (const float*)d_in[5];
    const float* ag1d = (const float*)d_in[6];
    const float* bg1 = (const float*)d_in[7];
    const float* W2 = (const float*)d_in[8];
    const float* b2 = (const float*)d_in[9];
    const float* Wg2 = (const float*)d_in[10];
    const float* ag2s = (const float*)d_in[11];
    const float* ag2d = (const float*)d_in[12];
    const float* bg2 = (const float*)d_in[13];

    float* enc = (float*)d_out;             // [NN,128]
    float* dec = enc + (size_t)NN * 128;    // [NN,64]

    float* ws = (float*)d_ws;
    float* bufA = ws;                       // NN*128
    float* bufB = bufA + (size_t)NN * 128;  // NN*128
    float* dinv = bufB + (size_t)NN * 128;  // NN
    float* asrc = dinv + NN;                // NN
    float* adst = asrc + NN;                // NN
    int* cnt = (int*)(adst + NN);           // NN
    int* rowptr = cnt + NN;                 // NN+1
    int* cursor = rowptr + NN + 1;          // NN
    int* csr_src = cursor + NN;             // NE

    const int TB = 256;
    int gN = (NN + TB - 1) / TB;
    int gE = (NE + TB - 1) / TB;
    int gScal = (NN + 3) / 4;

    // ---- CSR build (per call; graph-safe, deterministic set semantics) ----
    k_zero_int<<<gN, TB, 0, stream>>>(cnt, NN);
    k_count<<<gE, TB, 0, stream>>>(dst, cnt);
    k_scan<<<1, SCAN_T, 0, stream>>>(cnt, rowptr, cursor);
    k_fill<<<gE, TB, 0, stream>>>(src, dst, cursor, csr_src);
    k_dinv<<<gN, TB, 0, stream>>>(rowptr, dinv);

    // ---- Layer 1: GCN 128->128 + ReLU -> bufB ----
    k_gemm<<<NN, 128, 128 * sizeof(float), stream>>>(x, W1, bufA, 128, 128);
    k_gcn_gather<<<NN, 128, 0, stream>>>(rowptr, csr_src, bufA, dinv, b1, bufB, 128);

    // ---- Layer 2: GAT 128->128 -> encoded ----
    k_gemm<<<NN, 128, 128 * sizeof(float), stream>>>(bufB, Wg1, bufA, 128, 128);
    k_gat_scalars<<<gScal, TB, 0, stream>>>(bufA, ag1s, ag1d, asrc, adst, 128);
    k_gat_gather<<<NN, 128, 0, stream>>>(rowptr, csr_src, bufA, asrc, adst, bg1, enc, 128);

    // ---- Layer 3: GCN 128->64 + ReLU -> bufB ----
    k_gemm<<<NN, 64, 128 * sizeof(float), stream>>>(enc, W2, bufA, 128, 64);
    k_gcn_gather<<<NN, 64, 0, stream>>>(rowptr, csr_src, bufA, dinv, b2, bufB, 64);

    // ---- Layer 4: GAT 64->64 -> decoded ----
    k_gemm<<<NN, 64, 64 * sizeof(float), stream>>>(bufB, Wg2, bufA, 64, 64);
    k_gat_scalars<<<gScal, TB, 0, stream>>>(bufA, ag2s, ag2d, asrc, adst, 64);
    k_gat_gather<<<NN, 64, 0, stream>>>(rowptr, csr_src, bufA, asrc, adst, bg2, dec, 64);
}

// Round 3
// 427.563 us; speedup vs baseline: 3.0874x; 1.3426x over previous
//
#include <hip/hip_runtime.h>

#define NN 40000
#define NE 640000
#define SCAN_T 1024
#define SCAN_PER 40  // 1024*40 = 40960 >= NN
#define CHUNK 256

static __device__ __forceinline__ float lrelu(float x) { return x > 0.0f ? x : 0.2f * x; }

// ---------------- tiled GEMM: Y[r][c] = sum_k X[r][k] * W[k][c] ----------------
// Block: 64 rows x 64 cols, 256 threads, 4x4 register tile per thread.
// grid = (NN/64, FOUT/64). W panel + padded X tile staged in LDS.
template <int FIN, int FOUT>
__global__ __launch_bounds__(256) void k_gemm_t(const float* __restrict__ X,
                                                const float* __restrict__ W,
                                                float* __restrict__ Y) {
    constexpr int XLD = FIN + 4;  // pad to break 4-row-stride bank aliasing
    __shared__ float ws[FIN * 64];
    __shared__ float xs[64 * XLD];
    const int t = threadIdx.x;
    const int row0 = blockIdx.x * 64;
    const int col0 = blockIdx.y * 64;

    // cooperative load: W panel [FIN x 64]
    for (int i = t; i < FIN * 16; i += 256) {
        int k = i >> 4, cc = (i & 15) << 2;
        *(float4*)&ws[k * 64 + cc] = *(const float4*)&W[k * FOUT + col0 + cc];
    }
    // cooperative load: X tile [64 x FIN] (padded LDS rows)
    for (int i = t; i < 64 * (FIN / 4); i += 256) {
        int r = i / (FIN / 4), kk = (i % (FIN / 4)) << 2;
        *(float4*)&xs[r * XLD + kk] = *(const float4*)&X[(size_t)(row0 + r) * FIN + kk];
    }
    __syncthreads();

    const int c0 = (t & 15) << 2;  // 0..60
    const int r0 = (t >> 4) << 2;  // 0..60
    float acc[4][4] = {};
#pragma unroll 2
    for (int k = 0; k < FIN; k += 4) {
        float4 xv[4], wv[4];
#pragma unroll
        for (int i = 0; i < 4; ++i) xv[i] = *(const float4*)&xs[(r0 + i) * XLD + k];
#pragma unroll
        for (int j = 0; j < 4; ++j) wv[j] = *(const float4*)&ws[(k + j) * 64 + c0];
#pragma unroll
        for (int i = 0; i < 4; ++i) {
            acc[i][0] = fmaf(xv[i].x, wv[0].x, acc[i][0]);
            acc[i][1] = fmaf(xv[i].x, wv[0].y, acc[i][1]);
            acc[i][2] = fmaf(xv[i].x, wv[0].z, acc[i][2]);
            acc[i][3] = fmaf(xv[i].x, wv[0].w, acc[i][3]);
            acc[i][0] = fmaf(xv[i].y, wv[1].x, acc[i][0]);
            acc[i][1] = fmaf(xv[i].y, wv[1].y, acc[i][1]);
            acc[i][2] = fmaf(xv[i].y, wv[1].z, acc[i][2]);
            acc[i][3] = fmaf(xv[i].y, wv[1].w, acc[i][3]);
            acc[i][0] = fmaf(xv[i].z, wv[2].x, acc[i][0]);
            acc[i][1] = fmaf(xv[i].z, wv[2].y, acc[i][1]);
            acc[i][2] = fmaf(xv[i].z, wv[2].z, acc[i][2]);
            acc[i][3] = fmaf(xv[i].z, wv[2].w, acc[i][3]);
            acc[i][0] = fmaf(xv[i].w, wv[3].x, acc[i][0]);
            acc[i][1] = fmaf(xv[i].w, wv[3].y, acc[i][1]);
            acc[i][2] = fmaf(xv[i].w, wv[3].z, acc[i][2]);
            acc[i][3] = fmaf(xv[i].w, wv[3].w, acc[i][3]);
        }
    }
#pragma unroll
    for (int i = 0; i < 4; ++i) {
        float4 v = make_float4(acc[i][0], acc[i][1], acc[i][2], acc[i][3]);
        *(float4*)&Y[(size_t)(row0 + r0 + i) * FOUT + col0 + c0] = v;
    }
}

// ---------------- CSR build ----------------
__global__ void k_zero_int(int* __restrict__ p, int n) {
    int i = blockIdx.x * blockDim.x + threadIdx.x;
    if (i < n) p[i] = 0;
}
__global__ void k_count(const int* __restrict__ dst, int* __restrict__ cnt) {
    int e = blockIdx.x * blockDim.x + threadIdx.x;
    if (e < NE) atomicAdd(&cnt[dst[e]], 1);
}
__global__ void k_scan(const int* __restrict__ cnt, int* __restrict__ rowptr,
                       int* __restrict__ cursor) {
    __shared__ int tsum[SCAN_T];
    int t = threadIdx.x;
    int lo = t * SCAN_PER;
    int hi = lo + SCAN_PER;
    if (hi > NN) hi = NN;
    int s = 0;
    for (int i = lo; i < hi; ++i) s += cnt[i];
    tsum[t] = s;
    __syncthreads();
    for (int off = 1; off < SCAN_T; off <<= 1) {
        int v = (t >= off) ? tsum[t - off] : 0;
        __syncthreads();
        tsum[t] += v;
        __syncthreads();
    }
    int run = (t > 0) ? tsum[t - 1] : 0;
    for (int i = lo; i < hi; ++i) {
        rowptr[i] = run;
        cursor[i] = run;
        run += cnt[i];
    }
    if (t == SCAN_T - 1) rowptr[NN] = tsum[SCAN_T - 1];
}
__global__ void k_fill(const int* __restrict__ src, const int* __restrict__ dst,
                       int* __restrict__ cursor, int* __restrict__ csr_src) {
    int e = blockIdx.x * blockDim.x + threadIdx.x;
    if (e < NE) {
        int p = atomicAdd(&cursor[dst[e]], 1);
        csr_src[p] = src[e];
    }
}
__global__ void k_dinv(const int* __restrict__ rowptr, float* __restrict__ dinv) {
    int i = blockIdx.x * blockDim.x + threadIdx.x;
    if (i < NN) dinv[i] = rsqrtf(1.0f + (float)(rowptr[i + 1] - rowptr[i]));
}

// ---------------- GCN: gather aggregation, one block per dst node ----------------
__global__ void k_gcn_gather(const int* __restrict__ rowptr, const int* __restrict__ csr_src,
                             const float* __restrict__ h, const float* __restrict__ dinv,
                             const float* __restrict__ b, float* __restrict__ out, int F) {
    __shared__ int sbuf[CHUNK];
    __shared__ float wbuf[CHUNK];
    int d = blockIdx.x;
    int c = threadIdx.x;
    int beg = rowptr[d], end = rowptr[d + 1];
    float dd = dinv[d];
    float acc = h[(size_t)d * F + c] * dd;
    for (int base = beg; base < end; base += CHUNK) {
        int cnt = end - base;
        if (cnt > CHUNK) cnt = CHUNK;
        for (int j = c; j < cnt; j += F) {
            int s = csr_src[base + j];
            sbuf[j] = s;
            wbuf[j] = dinv[s];
        }
        __syncthreads();
        for (int j = 0; j < cnt; ++j) acc = fmaf(wbuf[j], h[(size_t)sbuf[j] * F + c], acc);
        __syncthreads();
    }
    out[(size_t)d * F + c] = fmaxf(fmaf(acc, dd, b[c]), 0.0f);
}

// ---------------- GAT per-node attention scalars ----------------
__global__ void k_gat_scalars(const float* __restrict__ hg, const float* __restrict__ a_s,
                              const float* __restrict__ a_d, float* __restrict__ asrc,
                              float* __restrict__ adst, int F) {
    int node = blockIdx.x * (blockDim.x >> 6) + (threadIdx.x >> 6);
    int lane = threadIdx.x & 63;
    if (node >= NN) return;
    float s = 0.0f, d = 0.0f;
    for (int c = lane; c < F; c += 64) {
        float v = hg[(size_t)node * F + c];
        s += v * a_s[c];
        d += v * a_d[c];
    }
    for (int off = 32; off; off >>= 1) {
        s += __shfl_down(s, off);
        d += __shfl_down(d, off);
    }
    if (lane == 0) {
        asrc[node] = s;
        adst[node] = d;
    }
}

// ---------------- GAT: fused softmax + gather, one block per dst node ----------------
__global__ void k_gat_gather(const int* __restrict__ rowptr, const int* __restrict__ csr_src,
                             const float* __restrict__ hg, const float* __restrict__ asrc,
                             const float* __restrict__ adst, const float* __restrict__ b,
                             float* __restrict__ out, int F) {
    __shared__ int sbuf[CHUNK];
    __shared__ float wbuf[CHUNK];
    __shared__ float red[2];
    int d = blockIdx.x;
    int tid = threadIdx.x;
    int lane = tid & 63, wid = tid >> 6, nw = F >> 6;
    int beg = rowptr[d], end = rowptr[d + 1];
    float ad = adst[d];
    float slog = lrelu(asrc[d] + ad);

    // phase 1: segment max (incl. self)
    float lm = slog;
    for (int j = beg + tid; j < end; j += F) {
        int s = csr_src[j];
        lm = fmaxf(lm, lrelu(asrc[s] + ad));
    }
    for (int off = 32; off; off >>= 1) lm = fmaxf(lm, __shfl_xor(lm, off));
    if (lane == 0) red[wid] = lm;
    __syncthreads();
    float m = red[0];
    for (int w = 1; w < nw; ++w) m = fmaxf(m, red[w]);
    __syncthreads();

    // phase 2: denominator
    float lz = 0.0f;
    for (int j = beg + tid; j < end; j += F) {
        int s = csr_src[j];
        lz += __expf(lrelu(asrc[s] + ad) - m);
    }
    for (int off = 32; off; off >>= 1) lz += __shfl_xor(lz, off);
    if (lane == 0) red[wid] = lz;
    __syncthreads();
    float eself = __expf(slog - m);
    float z = eself;
    for (int w = 0; w < nw; ++w) z += red[w];
    float zi = 1.0f / z;
    __syncthreads();

    // phase 3: weighted gather
    int c = tid;
    float acc = hg[(size_t)d * F + c] * (eself * zi);
    for (int base = beg; base < end; base += CHUNK) {
        int cnt = end - base;
        if (cnt > CHUNK) cnt = CHUNK;
        for (int j = tid; j < cnt; j += F) {
            int s = csr_src[base + j];
            sbuf[j] = s;
            wbuf[j] = __expf(lrelu(asrc[s] + ad) - m) * zi;
        }
        __syncthreads();
        for (int j = 0; j < cnt; ++j) acc = fmaf(wbuf[j], hg[(size_t)sbuf[j] * F + c], acc);
        __syncthreads();
    }
    out[(size_t)d * F + c] = acc + b[c];
}

extern "C" void kernel_launch(void* const* d_in, const int* in_sizes, int n_in,
                              void* d_out, int out_size, void* d_ws, size_t ws_size,
                              hipStream_t stream) {
    const float* x = (const float*)d_in[0];
    const int* src = (const int*)d_in[1];
    const int* dst = src + NE;
    const float* W1 = (const float*)d_in[2];
    const float* b1 = (const float*)d_in[3];
    const float* Wg1 = (const float*)d_in[4];
    const float* ag1s = (const float*)d_in[5];
    const float* ag1d = (const float*)d_in[6];
    const float* bg1 = (const float*)d_in[7];
    const float* W2 = (const float*)d_in[8];
    const float* b2 = (const float*)d_in[9];
    const float* Wg2 = (const float*)d_in[10];
    const float* ag2s = (const float*)d_in[11];
    const float* ag2d = (const float*)d_in[12];
    const float* bg2 = (const float*)d_in[13];

    float* enc = (float*)d_out;             // [NN,128]
    float* dec = enc + (size_t)NN * 128;    // [NN,64]

    float* ws = (float*)d_ws;
    float* bufA = ws;                       // NN*128
    float* bufB = bufA + (size_t)NN * 128;  // NN*128
    float* dinv = bufB + (size_t)NN * 128;  // NN
    float* asrc = dinv + NN;                // NN
    float* adst = asrc + NN;                // NN
    int* cnt = (int*)(adst + NN);           // NN
    int* rowptr = cnt + NN;                 // NN+1
    int* cursor = rowptr + NN + 1;          // NN
    int* csr_src = cursor + NN;             // NE

    const int TB = 256;
    int gN = (NN + TB - 1) / TB;
    int gE = (NE + TB - 1) / TB;
    int gScal = (NN + 3) / 4;

    // ---- CSR build ----
    k_zero_int<<<gN, TB, 0, stream>>>(cnt, NN);
    k_count<<<gE, TB, 0, stream>>>(dst, cnt);
    k_scan<<<1, SCAN_T, 0, stream>>>(cnt, rowptr, cursor);
    k_fill<<<gE, TB, 0, stream>>>(src, dst, cursor, csr_src);
    k_dinv<<<gN, TB, 0, stream>>>(rowptr, dinv);

    // ---- Layer 1: GCN 128->128 + ReLU -> bufB ----
    k_gemm_t<128, 128><<<dim3(NN / 64, 2), 256, 0, stream>>>(x, W1, bufA);
    k_gcn_gather<<<NN, 128, 0, stream>>>(rowptr, csr_src, bufA, dinv, b1, bufB, 128);

    // ---- Layer 2: GAT 128->128 -> encoded ----
    k_gemm_t<128, 128><<<dim3(NN / 64, 2), 256, 0, stream>>>(bufB, Wg1, bufA);
    k_gat_scalars<<<gScal, TB, 0, stream>>>(bufA, ag1s, ag1d, asrc, adst, 128);
    k_gat_gather<<<NN, 128, 0, stream>>>(rowptr, csr_src, bufA, asrc, adst, bg1, enc, 128);

    // ---- Layer 3: GCN 128->64 + ReLU -> bufB ----
    k_gemm_t<128, 64><<<dim3(NN / 64, 1), 256, 0, stream>>>(enc, W2, bufA);
    k_gcn_gather<<<NN, 64, 0, stream>>>(rowptr, csr_src, bufA, dinv, b2, bufB, 64);

    // ---- Layer 4: GAT 64->64 -> decoded ----
    k_gemm_t<64, 64><<<dim3(NN / 64, 1), 256, 0, stream>>>(bufB, Wg2, bufA);
    k_gat_scalars<<<gScal, TB, 0, stream>>>(bufA, ag2s, ag2d, asrc, adst, 64);
    k_gat_gather<<<NN, 64, 0, stream>>>(rowptr, csr_src, bufA, asrc, adst, bg2, dec, 64);
}

// Round 4
// 386.445 us; speedup vs baseline: 3.4159x; 1.1064x over previous
//
#include <hip/hip_runtime.h>

#define NN 40000
#define NE 640000
#define NSB ((NN + 255) / 256)  // 157 scan blocks

static __device__ __forceinline__ float lrelu(float x) { return x > 0.0f ? x : 0.2f * x; }

// ---------------- tiled GEMM: Y[r][c] = sum_k X[r][k] * W[k][c] ----------------
template <int FIN, int FOUT>
__global__ __launch_bounds__(256) void k_gemm_t(const float* __restrict__ X,
                                                const float* __restrict__ W,
                                                float* __restrict__ Y) {
    constexpr int XLD = FIN + 4;
    __shared__ float ws[FIN * 64];
    __shared__ float xs[64 * XLD];
    const int t = threadIdx.x;
    const int row0 = blockIdx.x * 64;
    const int col0 = blockIdx.y * 64;

    for (int i = t; i < FIN * 16; i += 256) {
        int k = i >> 4, cc = (i & 15) << 2;
        *(float4*)&ws[k * 64 + cc] = *(const float4*)&W[k * FOUT + col0 + cc];
    }
    for (int i = t; i < 64 * (FIN / 4); i += 256) {
        int r = i / (FIN / 4), kk = (i % (FIN / 4)) << 2;
        *(float4*)&xs[r * XLD + kk] = *(const float4*)&X[(size_t)(row0 + r) * FIN + kk];
    }
    __syncthreads();

    const int c0 = (t & 15) << 2;
    const int r0 = (t >> 4) << 2;
    float acc[4][4] = {};
#pragma unroll 2
    for (int k = 0; k < FIN; k += 4) {
        float4 xv[4], wv[4];
#pragma unroll
        for (int i = 0; i < 4; ++i) xv[i] = *(const float4*)&xs[(r0 + i) * XLD + k];
#pragma unroll
        for (int j = 0; j < 4; ++j) wv[j] = *(const float4*)&ws[(k + j) * 64 + c0];
#pragma unroll
        for (int i = 0; i < 4; ++i) {
            acc[i][0] = fmaf(xv[i].x, wv[0].x, acc[i][0]);
            acc[i][1] = fmaf(xv[i].x, wv[0].y, acc[i][1]);
            acc[i][2] = fmaf(xv[i].x, wv[0].z, acc[i][2]);
            acc[i][3] = fmaf(xv[i].x, wv[0].w, acc[i][3]);
            acc[i][0] = fmaf(xv[i].y, wv[1].x, acc[i][0]);
            acc[i][1] = fmaf(xv[i].y, wv[1].y, acc[i][1]);
            acc[i][2] = fmaf(xv[i].y, wv[1].z, acc[i][2]);
            acc[i][3] = fmaf(xv[i].y, wv[1].w, acc[i][3]);
            acc[i][0] = fmaf(xv[i].z, wv[2].x, acc[i][0]);
            acc[i][1] = fmaf(xv[i].z, wv[2].y, acc[i][1]);
            acc[i][2] = fmaf(xv[i].z, wv[2].z, acc[i][2]);
            acc[i][3] = fmaf(xv[i].z, wv[2].w, acc[i][3]);
            acc[i][0] = fmaf(xv[i].w, wv[3].x, acc[i][0]);
            acc[i][1] = fmaf(xv[i].w, wv[3].y, acc[i][1]);
            acc[i][2] = fmaf(xv[i].w, wv[3].z, acc[i][2]);
            acc[i][3] = fmaf(xv[i].w, wv[3].w, acc[i][3]);
        }
    }
#pragma unroll
    for (int i = 0; i < 4; ++i) {
        float4 v = make_float4(acc[i][0], acc[i][1], acc[i][2], acc[i][3]);
        *(float4*)&Y[(size_t)(row0 + r0 + i) * FOUT + col0 + c0] = v;
    }
}

// ---------------- CSR build ----------------
__global__ void k_zero_int(int* __restrict__ p, int n) {
    int i = blockIdx.x * blockDim.x + threadIdx.x;
    if (i < n) p[i] = 0;
}
__global__ void k_count(const int* __restrict__ dst, int* __restrict__ cnt) {
    int e = blockIdx.x * blockDim.x + threadIdx.x;
    if (e < NE) atomicAdd(&cnt[dst[e]], 1);
}
// hierarchical scan: per-block sums
__global__ void k_bsum(const int* __restrict__ cnt, int* __restrict__ bsum) {
    __shared__ int wsums[4];
    int i = blockIdx.x * 256 + threadIdx.x;
    int v = (i < NN) ? cnt[i] : 0;
    for (int off = 32; off; off >>= 1) v += __shfl_down(v, off);
    if ((threadIdx.x & 63) == 0) wsums[threadIdx.x >> 6] = v;
    __syncthreads();
    if (threadIdx.x == 0) bsum[blockIdx.x] = wsums[0] + wsums[1] + wsums[2] + wsums[3];
}
// scan the NSB (<=256) partials; also set rowptr[NN]=NE
__global__ void k_scanpart(const int* __restrict__ bsum, int* __restrict__ bofs,
                           int* __restrict__ rowptr) {
    __shared__ int s[256];
    int t = threadIdx.x;
    int v = (t < NSB) ? bsum[t] : 0;
    s[t] = v;
    __syncthreads();
    for (int off = 1; off < 256; off <<= 1) {
        int u = (t >= off) ? s[t - off] : 0;
        __syncthreads();
        s[t] += u;
        __syncthreads();
    }
    if (t < NSB) bofs[t] = s[t] - v;  // exclusive
    if (t == 0) rowptr[NN] = NE;
}
// per-block local exclusive scan + global offset -> rowptr, cursor
__global__ void k_scatter(const int* __restrict__ cnt, const int* __restrict__ bofs,
                          int* __restrict__ rowptr, int* __restrict__ cursor) {
    __shared__ int wsums[4];
    int t = threadIdx.x;
    int lane = t & 63, w = t >> 6;
    int i = blockIdx.x * 256 + t;
    int v = (i < NN) ? cnt[i] : 0;
    int x = v;
    for (int off = 1; off < 64; off <<= 1) {
        int u = __shfl_up(x, off);
        if (lane >= off) x += u;
    }
    if (lane == 63) wsums[w] = x;
    __syncthreads();
    int wofs = 0;
    for (int k = 0; k < w; ++k) wofs += wsums[k];
    int excl = bofs[blockIdx.x] + wofs + x - v;
    if (i < NN) {
        rowptr[i] = excl;
        cursor[i] = excl;
    }
}
__global__ void k_fill(const int* __restrict__ src, const int* __restrict__ dst,
                       int* __restrict__ cursor, int* __restrict__ csr_src) {
    int e = blockIdx.x * blockDim.x + threadIdx.x;
    if (e < NE) {
        int p = atomicAdd(&cursor[dst[e]], 1);
        csr_src[p] = src[e];
    }
}
__global__ void k_dinv(const int* __restrict__ rowptr, float* __restrict__ dinv) {
    int i = blockIdx.x * blockDim.x + threadIdx.x;
    if (i < NN) dinv[i] = rsqrtf(1.0f + (float)(rowptr[i + 1] - rowptr[i]));
}

// ---------------- GCN gather: one wave per node ----------------
template <int F>
__global__ __launch_bounds__(256) void k_gcn_gather_w(const int* __restrict__ rowptr,
                                                      const int* __restrict__ csr_src,
                                                      const float* __restrict__ h,
                                                      const float* __restrict__ dinv,
                                                      const float* __restrict__ b,
                                                      float* __restrict__ out) {
    constexpr int VEC = F / 64;
    int node = blockIdx.x * 4 + (threadIdx.x >> 6);
    int lane = threadIdx.x & 63;
    if (node >= NN) return;
    int beg = rowptr[node], end = rowptr[node + 1];
    float dd = dinv[node];
    float acc[VEC];
#pragma unroll
    for (int q = 0; q < VEC; ++q) acc[q] = h[(size_t)node * F + lane * VEC + q] * dd;

    for (int g = beg; g < end; g += 64) {
        int cnt = end - g;
        if (cnt > 64) cnt = 64;
        int myi = 0;
        float myw = 0.0f;
        if (lane < cnt) {
            int s = csr_src[g + lane];
            myi = s;
            myw = dinv[s];
        }
        for (int j = 0; j < cnt; ++j) {
            int s = __shfl(myi, j);
            float w = __shfl(myw, j);
            if constexpr (VEC == 2) {
                float2 v = *(const float2*)&h[(size_t)s * F + lane * 2];
                acc[0] = fmaf(w, v.x, acc[0]);
                acc[1] = fmaf(w, v.y, acc[1]);
            } else {
                acc[0] = fmaf(w, h[(size_t)s * F + lane], acc[0]);
            }
        }
    }
#pragma unroll
    for (int q = 0; q < VEC; ++q) {
        int c = lane * VEC + q;
        out[(size_t)node * F + c] = fmaxf(fmaf(acc[q], dd, b[c]), 0.0f);
    }
}

// ---------------- GAT per-node attention scalars ----------------
__global__ void k_gat_scalars(const float* __restrict__ hg, const float* __restrict__ a_s,
                              const float* __restrict__ a_d, float* __restrict__ asrc,
                              float* __restrict__ adst, int F) {
    int node = blockIdx.x * (blockDim.x >> 6) + (threadIdx.x >> 6);
    int lane = threadIdx.x & 63;
    if (node >= NN) return;
    float s = 0.0f, d = 0.0f;
    for (int c = lane; c < F; c += 64) {
        float v = hg[(size_t)node * F + c];
        s += v * a_s[c];
        d += v * a_d[c];
    }
    for (int off = 32; off; off >>= 1) {
        s += __shfl_down(s, off);
        d += __shfl_down(d, off);
    }
    if (lane == 0) {
        asrc[node] = s;
        adst[node] = d;
    }
}

// ---------------- GAT gather: one wave per node, fused softmax ----------------
template <int F>
__global__ __launch_bounds__(256) void k_gat_gather_w(const int* __restrict__ rowptr,
                                                      const int* __restrict__ csr_src,
                                                      const float* __restrict__ hg,
                                                      const float* __restrict__ asrc,
                                                      const float* __restrict__ adst,
                                                      const float* __restrict__ b,
                                                      float* __restrict__ out) {
    constexpr int VEC = F / 64;
    int node = blockIdx.x * 4 + (threadIdx.x >> 6);
    int lane = threadIdx.x & 63;
    if (node >= NN) return;
    int beg = rowptr[node], end = rowptr[node + 1];
    float ad = adst[node];
    float slog = lrelu(asrc[node] + ad);

    // segment max (incl. self)
    float lm = slog;
    for (int j = beg + lane; j < end; j += 64) lm = fmaxf(lm, lrelu(asrc[csr_src[j]] + ad));
    for (int off = 32; off; off >>= 1) lm = fmaxf(lm, __shfl_xor(lm, off));
    float m = lm;

    // denominator
    float lz = 0.0f;
    for (int j = beg + lane; j < end; j += 64) lz += __expf(lrelu(asrc[csr_src[j]] + ad) - m);
    for (int off = 32; off; off >>= 1) lz += __shfl_xor(lz, off);
    float eself = __expf(slog - m);
    float zi = 1.0f / (lz + eself);

    // weighted gather
    float acc[VEC];
    float wself = eself * zi;
#pragma unroll
    for (int q = 0; q < VEC; ++q) acc[q] = hg[(size_t)node * F + lane * VEC + q] * wself;

    for (int g = beg; g < end; g += 64) {
        int cnt = end - g;
        if (cnt > 64) cnt = 64;
        int myi = 0;
        float myw = 0.0f;
        if (lane < cnt) {
            int s = csr_src[g + lane];
            myi = s;
            myw = __expf(lrelu(asrc[s] + ad) - m) * zi;
        }
        for (int j = 0; j < cnt; ++j) {
            int s = __shfl(myi, j);
            float w = __shfl(myw, j);
            if constexpr (VEC == 2) {
                float2 v = *(const float2*)&hg[(size_t)s * F + lane * 2];
                acc[0] = fmaf(w, v.x, acc[0]);
                acc[1] = fmaf(w, v.y, acc[1]);
            } else {
                acc[0] = fmaf(w, hg[(size_t)s * F + lane], acc[0]);
            }
        }
    }
#pragma unroll
    for (int q = 0; q < VEC; ++q) {
        int c = lane * VEC + q;
        out[(size_t)node * F + c] = acc[q] + b[c];
    }
}

extern "C" void kernel_launch(void* const* d_in, const int* in_sizes, int n_in,
                              void* d_out, int out_size, void* d_ws, size_t ws_size,
                              hipStream_t stream) {
    const float* x = (const float*)d_in[0];
    const int* src = (const int*)d_in[1];
    const int* dst = src + NE;
    const float* W1 = (const float*)d_in[2];
    const float* b1 = (const float*)d_in[3];
    const float* Wg1 = (const float*)d_in[4];
    const float* ag1s = (const float*)d_in[5];
    const float* ag1d = (const float*)d_in[6];
    const float* bg1 = (const float*)d_in[7];
    const float* W2 = (const float*)d_in[8];
    const float* b2 = (const float*)d_in[9];
    const float* Wg2 = (const float*)d_in[10];
    const float* ag2s = (const float*)d_in[11];
    const float* ag2d = (const float*)d_in[12];
    const float* bg2 = (const float*)d_in[13];

    float* enc = (float*)d_out;             // [NN,128]
    float* dec = enc + (size_t)NN * 128;    // [NN,64]

    float* ws = (float*)d_ws;
    float* bufA = ws;                       // NN*128
    float* bufB = bufA + (size_t)NN * 128;  // NN*128
    float* dinv = bufB + (size_t)NN * 128;  // NN
    float* asrc = dinv + NN;                // NN
    float* adst = asrc + NN;                // NN
    int* cnt = (int*)(adst + NN);           // NN
    int* rowptr = cnt + NN;                 // NN+1
    int* cursor = rowptr + NN + 1;          // NN
    int* csr_src = cursor + NN;             // NE
    int* bsum = csr_src + NE;               // NSB
    int* bofs = bsum + NSB;                 // NSB

    const int TB = 256;
    int gN = (NN + TB - 1) / TB;
    int gE = (NE + TB - 1) / TB;
    int gScal = (NN + 3) / 4;
    int gWave = (NN + 3) / 4;

    // ---- CSR build ----
    k_zero_int<<<gN, TB, 0, stream>>>(cnt, NN);
    k_count<<<gE, TB, 0, stream>>>(dst, cnt);
    k_bsum<<<NSB, 256, 0, stream>>>(cnt, bsum);
    k_scanpart<<<1, 256, 0, stream>>>(bsum, bofs, rowptr);
    k_scatter<<<NSB, 256, 0, stream>>>(cnt, bofs, rowptr, cursor);
    k_fill<<<gE, TB, 0, stream>>>(src, dst, cursor, csr_src);
    k_dinv<<<gN, TB, 0, stream>>>(rowptr, dinv);

    // ---- Layer 1: GCN 128->128 + ReLU -> bufB ----
    k_gemm_t<128, 128><<<dim3(NN / 64, 2), 256, 0, stream>>>(x, W1, bufA);
    k_gcn_gather_w<128><<<gWave, 256, 0, stream>>>(rowptr, csr_src, bufA, dinv, b1, bufB);

    // ---- Layer 2: GAT 128->128 -> encoded ----
    k_gemm_t<128, 128><<<dim3(NN / 64, 2), 256, 0, stream>>>(bufB, Wg1, bufA);
    k_gat_scalars<<<gScal, TB, 0, stream>>>(bufA, ag1s, ag1d, asrc, adst, 128);
    k_gat_gather_w<128><<<gWave, 256, 0, stream>>>(rowptr, csr_src, bufA, asrc, adst, bg1, enc);

    // ---- Layer 3: GCN 128->64 + ReLU -> bufB ----
    k_gemm_t<128, 64><<<dim3(NN / 64, 1), 256, 0, stream>>>(enc, W2, bufA);
    k_gcn_gather_w<64><<<gWave, 256, 0, stream>>>(rowptr, csr_src, bufA, dinv, b2, bufB);

    // ---- Layer 4: GAT 64->64 -> decoded ----
    k_gemm_t<64, 64><<<dim3(NN / 64, 1), 256, 0, stream>>>(bufB, Wg2, bufA);
    k_gat_scalars<<<gScal, TB, 0, stream>>>(bufA, ag2s, ag2d, asrc, adst, 64);
    k_gat_gather_w<64><<<gWave, 256, 0, stream>>>(rowptr, csr_src, bufA, asrc, adst, bg2, dec);
}

// Round 5
// 315.062 us; speedup vs baseline: 4.1899x; 1.2266x over previous
//
#include <hip/hip_runtime.h>

#define NN 40000
#define NE 640000
#define NSB ((NN + 255) / 256)  // 157 scan blocks

static __device__ __forceinline__ float lrelu(float x) { return x > 0.0f ? x : 0.2f * x; }

static __device__ __forceinline__ float wave_max(float v) {
    for (int off = 32; off; off >>= 1) v = fmaxf(v, __shfl_xor(v, off));
    return v;
}
static __device__ __forceinline__ float wave_sum(float v) {
    for (int off = 32; off; off >>= 1) v += __shfl_xor(v, off);
    return v;
}

// ---------------- tiled GEMM: Y[r][c] = sum_k X[r][k] * W[k][c] ----------------
template <int FIN, int FOUT>
__global__ __launch_bounds__(256) void k_gemm_t(const float* __restrict__ X,
                                                const float* __restrict__ W,
                                                float* __restrict__ Y) {
    constexpr int XLD = FIN + 4;
    __shared__ float ws[FIN * 64];
    __shared__ float xs[64 * XLD];
    const int t = threadIdx.x;
    const int row0 = blockIdx.x * 64;
    const int col0 = blockIdx.y * 64;

    for (int i = t; i < FIN * 16; i += 256) {
        int k = i >> 4, cc = (i & 15) << 2;
        *(float4*)&ws[k * 64 + cc] = *(const float4*)&W[k * FOUT + col0 + cc];
    }
    for (int i = t; i < 64 * (FIN / 4); i += 256) {
        int r = i / (FIN / 4), kk = (i % (FIN / 4)) << 2;
        *(float4*)&xs[r * XLD + kk] = *(const float4*)&X[(size_t)(row0 + r) * FIN + kk];
    }
    __syncthreads();

    const int c0 = (t & 15) << 2;
    const int r0 = (t >> 4) << 2;
    float acc[4][4] = {};
#pragma unroll 2
    for (int k = 0; k < FIN; k += 4) {
        float4 xv[4], wv[4];
#pragma unroll
        for (int i = 0; i < 4; ++i) xv[i] = *(const float4*)&xs[(r0 + i) * XLD + k];
#pragma unroll
        for (int j = 0; j < 4; ++j) wv[j] = *(const float4*)&ws[(k + j) * 64 + c0];
#pragma unroll
        for (int i = 0; i < 4; ++i) {
            acc[i][0] = fmaf(xv[i].x, wv[0].x, acc[i][0]);
            acc[i][1] = fmaf(xv[i].x, wv[0].y, acc[i][1]);
            acc[i][2] = fmaf(xv[i].x, wv[0].z, acc[i][2]);
            acc[i][3] = fmaf(xv[i].x, wv[0].w, acc[i][3]);
            acc[i][0] = fmaf(xv[i].y, wv[1].x, acc[i][0]);
            acc[i][1] = fmaf(xv[i].y, wv[1].y, acc[i][1]);
            acc[i][2] = fmaf(xv[i].y, wv[1].z, acc[i][2]);
            acc[i][3] = fmaf(xv[i].y, wv[1].w, acc[i][3]);
            acc[i][0] = fmaf(xv[i].z, wv[2].x, acc[i][0]);
            acc[i][1] = fmaf(xv[i].z, wv[2].y, acc[i][1]);
            acc[i][2] = fmaf(xv[i].z, wv[2].z, acc[i][2]);
            acc[i][3] = fmaf(xv[i].z, wv[2].w, acc[i][3]);
            acc[i][0] = fmaf(xv[i].w, wv[3].x, acc[i][0]);
            acc[i][1] = fmaf(xv[i].w, wv[3].y, acc[i][1]);
            acc[i][2] = fmaf(xv[i].w, wv[3].z, acc[i][2]);
            acc[i][3] = fmaf(xv[i].w, wv[3].w, acc[i][3]);
        }
    }
#pragma unroll
    for (int i = 0; i < 4; ++i) {
        float4 v = make_float4(acc[i][0], acc[i][1], acc[i][2], acc[i][3]);
        *(float4*)&Y[(size_t)(row0 + r0 + i) * FOUT + col0 + c0] = v;
    }
}

// ---------------- CSR build ----------------
__global__ void k_zero_int(int* __restrict__ p, int n) {
    int i = blockIdx.x * blockDim.x + threadIdx.x;
    if (i < n) p[i] = 0;
}
__global__ void k_count(const int* __restrict__ dst, int* __restrict__ cnt) {
    int e = blockIdx.x * blockDim.x + threadIdx.x;
    if (e < NE) atomicAdd(&cnt[dst[e]], 1);
}
__global__ void k_bsum(const int* __restrict__ cnt, int* __restrict__ bsum) {
    __shared__ int wsums[4];
    int i = blockIdx.x * 256 + threadIdx.x;
    int v = (i < NN) ? cnt[i] : 0;
    for (int off = 32; off; off >>= 1) v += __shfl_down(v, off);
    if ((threadIdx.x & 63) == 0) wsums[threadIdx.x >> 6] = v;
    __syncthreads();
    if (threadIdx.x == 0) bsum[blockIdx.x] = wsums[0] + wsums[1] + wsums[2] + wsums[3];
}
__global__ void k_scanpart(const int* __restrict__ bsum, int* __restrict__ bofs,
                           int* __restrict__ rowptr) {
    __shared__ int s[256];
    int t = threadIdx.x;
    int v = (t < NSB) ? bsum[t] : 0;
    s[t] = v;
    __syncthreads();
    for (int off = 1; off < 256; off <<= 1) {
        int u = (t >= off) ? s[t - off] : 0;
        __syncthreads();
        s[t] += u;
        __syncthreads();
    }
    if (t < NSB) bofs[t] = s[t] - v;
    if (t == 0) rowptr[NN] = NE;
}
__global__ void k_scatter(const int* __restrict__ cnt, const int* __restrict__ bofs,
                          int* __restrict__ rowptr, int* __restrict__ cursor) {
    __shared__ int wsums[4];
    int t = threadIdx.x;
    int lane = t & 63, w = t >> 6;
    int i = blockIdx.x * 256 + t;
    int v = (i < NN) ? cnt[i] : 0;
    int x = v;
    for (int off = 1; off < 64; off <<= 1) {
        int u = __shfl_up(x, off);
        if (lane >= off) x += u;
    }
    if (lane == 63) wsums[w] = x;
    __syncthreads();
    int wofs = 0;
    for (int k = 0; k < w; ++k) wofs += wsums[k];
    int excl = bofs[blockIdx.x] + wofs + x - v;
    if (i < NN) {
        rowptr[i] = excl;
        cursor[i] = excl;
    }
}
__global__ void k_fill(const int* __restrict__ src, const int* __restrict__ dst,
                       int* __restrict__ cursor, int* __restrict__ csr_src) {
    int e = blockIdx.x * blockDim.x + threadIdx.x;
    if (e < NE) {
        int p = atomicAdd(&cursor[dst[e]], 1);
        csr_src[p] = src[e];
    }
}
__global__ void k_dinv(const int* __restrict__ rowptr, float* __restrict__ dinv) {
    int i = blockIdx.x * blockDim.x + threadIdx.x;
    if (i < NN) dinv[i] = rsqrtf(1.0f + (float)(rowptr[i + 1] - rowptr[i]));
}

// ---- 8-way padded gather step: 8 shuffles -> 8 loads in flight -> 16 FMAs ----
template <int F>
static __device__ __forceinline__ void gather8(const float* __restrict__ h, int lane, int myi,
                                               float myw, int cnt, float* acc) {
    for (int j = 0; j < cnt; j += 8) {
        int s[8];
        float w[8];
#pragma unroll
        for (int u = 0; u < 8; ++u) {
            s[u] = __shfl(myi, j + u);
            w[u] = __shfl(myw, j + u);
        }
        if constexpr (F == 128) {
            float2 v[8];
#pragma unroll
            for (int u = 0; u < 8; ++u) v[u] = *(const float2*)&h[(size_t)s[u] * F + lane * 2];
#pragma unroll
            for (int u = 0; u < 8; ++u) {
                acc[0] = fmaf(w[u], v[u].x, acc[0]);
                acc[1] = fmaf(w[u], v[u].y, acc[1]);
            }
        } else {
            float v[8];
#pragma unroll
            for (int u = 0; u < 8; ++u) v[u] = h[(size_t)s[u] * F + lane];
#pragma unroll
            for (int u = 0; u < 8; ++u) acc[0] = fmaf(w[u], v[u], acc[0]);
        }
    }
}

// ---------------- GCN gather: one wave per node ----------------
template <int F>
__global__ __launch_bounds__(256) void k_gcn_gather_w(const int* __restrict__ rowptr,
                                                      const int* __restrict__ csr_src,
                                                      const float* __restrict__ h,
                                                      const float* __restrict__ dinv,
                                                      const float* __restrict__ b,
                                                      float* __restrict__ out) {
    constexpr int VEC = F / 64;
    int node = blockIdx.x * 4 + (threadIdx.x >> 6);
    int lane = threadIdx.x & 63;
    if (node >= NN) return;
    int beg = rowptr[node], end = rowptr[node + 1];
    float dd = dinv[node];
    float acc[VEC];
#pragma unroll
    for (int q = 0; q < VEC; ++q) acc[q] = h[(size_t)node * F + lane * VEC + q] * dd;

    for (int g = beg; g < end; g += 64) {
        int cnt = end - g;
        if (cnt > 64) cnt = 64;
        int myi = node;
        float myw = 0.0f;
        if (lane < cnt) {
            int s = csr_src[g + lane];
            myi = s;
            myw = dinv[s];
        }
        gather8<F>(h, lane, myi, myw, cnt, acc);
    }
#pragma unroll
    for (int q = 0; q < VEC; ++q) {
        int c = lane * VEC + q;
        out[(size_t)node * F + c] = fmaxf(fmaf(acc[q], dd, b[c]), 0.0f);
    }
}

// ---------------- GAT per-node attention scalars ----------------
__global__ void k_gat_scalars(const float* __restrict__ hg, const float* __restrict__ a_s,
                              const float* __restrict__ a_d, float* __restrict__ asrc,
                              float* __restrict__ adst, int F) {
    int node = blockIdx.x * (blockDim.x >> 6) + (threadIdx.x >> 6);
    int lane = threadIdx.x & 63;
    if (node >= NN) return;
    float s = 0.0f, d = 0.0f;
    for (int c = lane; c < F; c += 64) {
        float v = hg[(size_t)node * F + c];
        s += v * a_s[c];
        d += v * a_d[c];
    }
    for (int off = 32; off; off >>= 1) {
        s += __shfl_down(s, off);
        d += __shfl_down(d, off);
    }
    if (lane == 0) {
        asrc[node] = s;
        adst[node] = d;
    }
}

// ---------------- GAT gather: one wave per node, fused single-pass softmax ----------------
template <int F>
__global__ __launch_bounds__(256) void k_gat_gather_w(const int* __restrict__ rowptr,
                                                      const int* __restrict__ csr_src,
                                                      const float* __restrict__ hg,
                                                      const float* __restrict__ asrc,
                                                      const float* __restrict__ adst,
                                                      const float* __restrict__ b,
                                                      float* __restrict__ out) {
    constexpr int VEC = F / 64;
    int node = blockIdx.x * 4 + (threadIdx.x >> 6);
    int lane = threadIdx.x & 63;
    if (node >= NN) return;
    int beg = rowptr[node], end = rowptr[node + 1];
    int deg = end - beg;
    float ad = adst[node];
    float slog = lrelu(asrc[node] + ad);
    float acc[VEC];

    if (deg <= 64) {
        // single pass: lane's edge logit lives in a register
        int myi = node;
        float logit = -1e30f;
        if (lane < deg) {
            myi = csr_src[beg + lane];
            logit = lrelu(asrc[myi] + ad);
        }
        float m = fmaxf(slog, wave_max(logit));
        float e = (lane < deg) ? __expf(logit - m) : 0.0f;
        float z = wave_sum(e) + __expf(slog - m);
        float zi = 1.0f / z;
        float myw = e * zi;
        float wself = __expf(slog - m) * zi;
#pragma unroll
        for (int q = 0; q < VEC; ++q) acc[q] = hg[(size_t)node * F + lane * VEC + q] * wself;
        gather8<F>(hg, lane, myi, myw, deg, acc);
    } else {
        // generic multi-chunk path (rare)
        float lm = slog;
        for (int j = beg + lane; j < end; j += 64) lm = fmaxf(lm, lrelu(asrc[csr_src[j]] + ad));
        float m = wave_max(lm);
        float lz = 0.0f;
        for (int j = beg + lane; j < end; j += 64)
            lz += __expf(lrelu(asrc[csr_src[j]] + ad) - m);
        float z = wave_sum(lz) + __expf(slog - m);
        float zi = 1.0f / z;
        float wself = __expf(slog - m) * zi;
#pragma unroll
        for (int q = 0; q < VEC; ++q) acc[q] = hg[(size_t)node * F + lane * VEC + q] * wself;
        for (int g = beg; g < end; g += 64) {
            int cnt = end - g;
            if (cnt > 64) cnt = 64;
            int myi = node;
            float myw = 0.0f;
            if (lane < cnt) {
                int s = csr_src[g + lane];
                myi = s;
                myw = __expf(lrelu(asrc[s] + ad) - m) * zi;
            }
            gather8<F>(hg, lane, myi, myw, cnt, acc);
        }
    }
#pragma unroll
    for (int q = 0; q < VEC; ++q) {
        int c = lane * VEC + q;
        out[(size_t)node * F + c] = acc[q] + b[c];
    }
}

extern "C" void kernel_launch(void* const* d_in, const int* in_sizes, int n_in,
                              void* d_out, int out_size, void* d_ws, size_t ws_size,
                              hipStream_t stream) {
    const float* x = (const float*)d_in[0];
    const int* src = (const int*)d_in[1];
    const int* dst = src + NE;
    const float* W1 = (const float*)d_in[2];
    const float* b1 = (const float*)d_in[3];
    const float* Wg1 = (const float*)d_in[4];
    const float* ag1s = (const float*)d_in[5];
    const float* ag1d = (const float*)d_in[6];
    const float* bg1 = (const float*)d_in[7];
    const float* W2 = (const float*)d_in[8];
    const float* b2 = (const float*)d_in[9];
    const float* Wg2 = (const float*)d_in[10];
    const float* ag2s = (const float*)d_in[11];
    const float* ag2d = (const float*)d_in[12];
    const float* bg2 = (const float*)d_in[13];

    float* enc = (float*)d_out;             // [NN,128]
    float* dec = enc + (size_t)NN * 128;    // [NN,64]

    float* ws = (float*)d_ws;
    float* bufA = ws;                       // NN*128
    float* bufB = bufA + (size_t)NN * 128;  // NN*128
    float* dinv = bufB + (size_t)NN * 128;  // NN
    float* asrc = dinv + NN;                // NN
    float* adst = asrc + NN;                // NN
    int* cnt = (int*)(adst + NN);           // NN
    int* rowptr = cnt + NN;                 // NN+1
    int* cursor = rowptr + NN + 1;          // NN
    int* csr_src = cursor + NN;             // NE
    int* bsum = csr_src + NE;               // NSB
    int* bofs = bsum + NSB;                 // NSB

    const int TB = 256;
    int gN = (NN + TB - 1) / TB;
    int gE = (NE + TB - 1) / TB;
    int gScal = (NN + 3) / 4;
    int gWave = (NN + 3) / 4;

    // ---- CSR build ----
    k_zero_int<<<gN, TB, 0, stream>>>(cnt, NN);
    k_count<<<gE, TB, 0, stream>>>(dst, cnt);
    k_bsum<<<NSB, 256, 0, stream>>>(cnt, bsum);
    k_scanpart<<<1, 256, 0, stream>>>(bsum, bofs, rowptr);
    k_scatter<<<NSB, 256, 0, stream>>>(cnt, bofs, rowptr, cursor);
    k_fill<<<gE, TB, 0, stream>>>(src, dst, cursor, csr_src);
    k_dinv<<<gN, TB, 0, stream>>>(rowptr, dinv);

    // ---- Layer 1: GCN 128->128 + ReLU -> bufB ----
    k_gemm_t<128, 128><<<dim3(NN / 64, 2), 256, 0, stream>>>(x, W1, bufA);
    k_gcn_gather_w<128><<<gWave, 256, 0, stream>>>(rowptr, csr_src, bufA, dinv, b1, bufB);

    // ---- Layer 2: GAT 128->128 -> encoded ----
    k_gemm_t<128, 128><<<dim3(NN / 64, 2), 256, 0, stream>>>(bufB, Wg1, bufA);
    k_gat_scalars<<<gScal, TB, 0, stream>>>(bufA, ag1s, ag1d, asrc, adst, 128);
    k_gat_gather_w<128><<<gWave, 256, 0, stream>>>(rowptr, csr_src, bufA, asrc, adst, bg1, enc);

    // ---- Layer 3: GCN 128->64 + ReLU -> bufB ----
    k_gemm_t<128, 64><<<dim3(NN / 64, 1), 256, 0, stream>>>(enc, W2, bufA);
    k_gcn_gather_w<64><<<gWave, 256, 0, stream>>>(rowptr, csr_src, bufA, dinv, b2, bufB);

    // ---- Layer 4: GAT 64->64 -> decoded ----
    k_gemm_t<64, 64><<<dim3(NN / 64, 1), 256, 0, stream>>>(bufB, Wg2, bufA);
    k_gat_scalars<<<gScal, TB, 0, stream>>>(bufA, ag2s, ag2d, asrc, adst, 64);
    k_gat_gather_w<64><<<gWave, 256, 0, stream>>>(rowptr, csr_src, bufA, asrc, adst, bg2, dec);
}